// Round 5
// baseline (742.189 us; speedup 1.0000x reference)
//
#include <hip/hip_runtime.h>
#include <hip/hip_bf16.h>
#include <math.h>

// Problem constants
#define NTOK  4096      // B*T
#define CDIM  1024
#define HDIM  4096
#define NEXP  8
#define TOPK  2

using short8 = __attribute__((ext_vector_type(8))) short;
using f32x4  = __attribute__((ext_vector_type(4))) float;

__device__ inline ushort f2bf(float f) {
    uint32_t u = __builtin_bit_cast(uint32_t, f);
    uint32_t r = (u + 0x7FFFu + ((u >> 16) & 1u)) >> 16;
    return (ushort)r;
}

// gelu(v) = 0.5 v (1 + erf(v/sqrt2)); erf via Abramowitz-Stegun 7.1.26,
// |abs err| <= 1.5e-7 -- ~5000x below the bf16 rounding floor of h.
__device__ __forceinline__ float gelu_fast(float v) {
    float z = fabsf(v) * 0.70710678118654752f;
    float t = 1.0f / fmaf(0.3275911f, z, 1.0f);
    float p = t * fmaf(t, fmaf(t, fmaf(t, fmaf(t, 1.061405429f, -1.453152027f),
                                        1.421413741f), -0.284496736f), 0.254829592f);
    float erfz = 1.0f - p * __expf(-z * z);
    return 0.5f * v * (1.0f + copysignf(erfz, v));
}

// async global->LDS, 16 B per lane; LDS dest = wave-uniform base + lane*16
__device__ __forceinline__ void gl_lds16(const void* g, void* l) {
    __builtin_amdgcn_global_load_lds(
        (const __attribute__((address_space(1))) void*)(void*)g,
        (__attribute__((address_space(3))) void*)l, 16, 0, 0);
}

#define SCHED_FENCE() __builtin_amdgcn_sched_barrier(0)
#define RAW_BAR()  { SCHED_FENCE(); __builtin_amdgcn_s_barrier(); SCHED_FENCE(); }
#define VMWAIT(N)  { asm volatile("s_waitcnt vmcnt(" #N ")" ::: "memory"); SCHED_FENCE(); }
#define LGKM0()    { asm volatile("s_waitcnt lgkmcnt(0)" ::: "memory"); SCHED_FENCE(); }

// ---------------------------------------------------------------------------
// Gate: one wave per token. fp32 logits, top-2, normalized weights.
// Also converts x to bf16.
__global__ __launch_bounds__(256)
void gate_kernel(const float* __restrict__ x, const float* __restrict__ Wg,
                 const float* __restrict__ bg, int* __restrict__ counts,
                 int* __restrict__ tlist, float* __restrict__ wslot,
                 ushort* __restrict__ xbf) {
    int wave = threadIdx.x >> 6, lane = threadIdx.x & 63;
    int t = blockIdx.x * 4 + wave;
    const float* xr = x + (size_t)t * CDIM;

    float acc[NEXP];
#pragma unroll
    for (int e = 0; e < NEXP; e++) acc[e] = 0.f;

#pragma unroll
    for (int i = 0; i < CDIM / 64; i++) {
        int c = lane + 64 * i;
        float xv = xr[c];
        xbf[(size_t)t * CDIM + c] = f2bf(xv);
        const float* wr = Wg + (size_t)c * NEXP;
#pragma unroll
        for (int e = 0; e < NEXP; e++) acc[e] += xv * wr[e];
    }
#pragma unroll
    for (int e = 0; e < NEXP; e++) {
        float v = acc[e];
        for (int off = 32; off > 0; off >>= 1) v += __shfl_xor(v, off);
        acc[e] = v + bg[e];
    }
    if (lane == 0) {
        int i1 = 0; float m1 = acc[0];
#pragma unroll
        for (int e = 1; e < NEXP; e++) if (acc[e] > m1) { m1 = acc[e]; i1 = e; }
        int i2 = -1; float m2 = -1e30f;
#pragma unroll
        for (int e = 0; e < NEXP; e++) if (e != i1 && acc[e] > m2) { m2 = acc[e]; i2 = e; }
        // softmax top-2 renormalized: w0 = g1/(g1+g2) = 1/(1+exp(l2-l1))
        float w0 = 1.f / (1.f + expf(m2 - m1));
        float w1 = 1.f - w0;
        int p0 = atomicAdd(&counts[i1], 1);
        tlist[i1 * NTOK + p0] = t * 2;
        int p1 = atomicAdd(&counts[i2], 1);
        tlist[i2 * NTOK + p1] = t * 2 + 1;
        wslot[t * 2]     = w0;
        wslot[t * 2 + 1] = w1;
    }
}

// ---------------------------------------------------------------------------
// Sparse-expert GEMM, B consumed in NATIVE f32 [K][N] layout (transpose +
// bf16 conversion fused into staging -- the standalone transpose kernels ran
// at ~1.5 TB/s due to strided 128B write bursts and cost ~300 us/iter).
//   A : bf16 [*, K], row index = tlist_value >> ashift  (gl_lds staged)
//   W : f32  [E][K][N] native                            (reg-staged)
//   Out: row index = tlist_value; bf16 (h) or f32 (y)
// 128x128 tile, BK=32, 4 waves x (64x64), v_mfma_f32_16x16x32_bf16.
//
// B reg-staging (T14): per K-step each thread loads 4x float4 from 4
// consecutive k-rows (wave = 2 rows x 512B contiguous), packs a 4x4
// in-register transpose into 4x uint2 of K-consecutive bf16, ds_write_b64
// into Bs with the SAME chunk swizzle the fragment reads use:
//   granule q (= k 4q..4q+3) of row n -> byte n*64 + (((q>>1)^((n>>1)&3))<<4)
//   + (q&1)*8.  Read side (unchanged): chunk quad^((l16>>1)&3).
//
// vmcnt discipline (T4): 6 vmem/step/thread (4 B-loads + 2 A-gl_lds),
// prefetch 1 step ahead -> steady 12 outstanding, vmcnt(6) retires exactly
// the current step's ops. lgkmcnt(0) before barrier-1 (raw s_barrier does
// not drain the ds_writes). Two named B-register sets (no dynamic indexing).
//
// 1-D grid, expert->XCD partition (bijective decode; G16-safe).
// Split-K (GEMM2 only): separate partial buffers, no atomics.
template<int GELU, int OUTBF16>
__global__ __launch_bounds__(256, 3)
void moe_gemm(const ushort* __restrict__ A, const float* __restrict__ W,
              const float* __restrict__ bias, const int* __restrict__ tlist,
              const int* __restrict__ counts, void* __restrict__ Out,
              int K, int N, int ashift, int nxmask, int nxshift, int ksplit,
              size_t psz) {
    int flat = blockIdx.x;
    int e  = flat & 7;
    int j  = flat >> 3;
    int mt = j & 31;              // m-tile innermost within an XCD
    int nj = j >> 5;
    int cnt = counts[e];
    int m0 = mt * 128;
    if (m0 >= cnt) return;
    int n0 = (nj & nxmask) * 128;
    int split = nj >> nxshift;
    int kbeg = split * ksplit;

    __shared__ ushort As[2][128 * 32];
    __shared__ ushort Bs[2][128 * 32];
    __shared__ int rowv[128];

    int tid = threadIdx.x;
    if (tid < 128) {
        int r = m0 + tid;
        rowv[tid] = tlist[e * NTOK + (r < cnt ? r : cnt - 1)];
    }
    __syncthreads();              // full drain: vmcnt baseline 0 for the loop

    const float* We = W + (size_t)e * K * N;

    int lane = tid & 63, w = tid >> 6;
    int wm = (w >> 1) * 64, wn = (w & 1) * 64;
    int quad = lane >> 4, l16 = lane & 15;

    // ---- A staging (unchanged): source chunk pre-swizzled, LDS linear.
    int srow   = tid >> 2;
    int schunk = (tid & 3) ^ ((tid >> 3) & 3);   // == q ^ ((srow>>1)&3)
    const ushort* pa0 = A + (size_t)(rowv[srow]      >> ashift) * K + kbeg + schunk * 8;
    const ushort* pa1 = A + (size_t)(rowv[srow + 64] >> ashift) * K + kbeg + schunk * 8;

    // ---- B staging: thread (q = tid>>5, g = tid&31) covers k = 4q..4q+3,
    //      n = 4g..4g+3 of the 32x128 native f32 tile.
    int q = tid >> 5, g = tid & 31;
    const float* pB = We + (size_t)(kbeg + 4 * q) * N + n0 + 4 * g;
    int boff[4];
#pragma unroll
    for (int i = 0; i < 4; i++) {
        int n = 4 * g + i;
        boff[i] = n * 64 + ((((q >> 1) ^ ((n >> 1) & 3))) << 4) + (q & 1) * 8;
    }

    // Fragment-read swizzle (unchanged): phys chunk = quad ^ ((l16>>1)&3).
    int swr  = quad ^ ((l16 >> 1) & 3);
    int aidx = (wm + l16) * 32 + swr * 8;
    int bidx = (wn + l16) * 32 + swr * 8;

    f32x4 acc[4][4] = {};
    f32x4 r0a, r0b, r0c, r0d, r1a, r1b, r1c, r1d;   // two named B reg sets

#define BLOAD(s) { \
        s##a = *(const f32x4*)(pB + 0 * (size_t)N); \
        s##b = *(const f32x4*)(pB + 1 * (size_t)N); \
        s##c = *(const f32x4*)(pB + 2 * (size_t)N); \
        s##d = *(const f32x4*)(pB + 3 * (size_t)N); \
        pB += 32 * (size_t)N; }

#define DSW(s, buf) { \
        char* bb = (char*)&Bs[buf][0]; \
        _Pragma("unroll") \
        for (int i = 0; i < 4; i++) { \
            uint2 pr; \
            pr.x = (uint)f2bf(s##a[i]) | ((uint)f2bf(s##b[i]) << 16); \
            pr.y = (uint)f2bf(s##c[i]) | ((uint)f2bf(s##d[i]) << 16); \
            *(uint2*)(bb + boff[i]) = pr; \
        } }

    auto AGLDS = [&](int buf) {
        gl_lds16(pa0, &As[buf][(w * 16) * 32]);
        gl_lds16(pa1, &As[buf][(w * 16 + 64) * 32]);
        pa0 += 32; pa1 += 32;
    };
    auto COMPUTE = [&](int buf) {
        short8 a[4], b[4];
#pragma unroll
        for (int mti = 0; mti < 4; mti++) a[mti] = *(short8*)&As[buf][aidx + mti * 512];
#pragma unroll
        for (int nti = 0; nti < 4; nti++) b[nti] = *(short8*)&Bs[buf][bidx + nti * 512];
#pragma unroll
        for (int mti = 0; mti < 4; mti++)
#pragma unroll
            for (int nti = 0; nti < 4; nti++)
                acc[mti][nti] = __builtin_amdgcn_mfma_f32_16x16x32_bf16(
                    a[mti], b[nti], acc[mti][nti], 0, 0, 0);
    };

    int nsteps = ksplit >> 5;     // 32 (GEMM1) or 64 (GEMM2 split) -- even
    BLOAD(r0); AGLDS(0);          // 6 outstanding
    for (int i = 0; i < nsteps - 2; i += 2) {
        BLOAD(r1); AGLDS(1);      // 12 outstanding
        VMWAIT(6);                // step-i ops retired (A(i) in LDS, r0 ready)
        DSW(r0, 0); LGKM0();
        RAW_BAR();                // all waves staged buf0
        COMPUTE(0);
        RAW_BAR();                // buf0 reads consumed
        BLOAD(r0); AGLDS(0);      // 12 outstanding
        VMWAIT(6);
        DSW(r1, 1); LGKM0();
        RAW_BAR();
        COMPUTE(1);
        RAW_BAR();
    }
    BLOAD(r1); AGLDS(1);          // final step's ops
    VMWAIT(6);
    DSW(r0, 0); LGKM0();
    RAW_BAR();
    COMPUTE(0);
    RAW_BAR();
    VMWAIT(0);
    DSW(r1, 1); LGKM0();
    RAW_BAR();
    COMPUTE(1);
#undef BLOAD
#undef DSW

    // Epilogue. C/D layout: col = lane&15, row = (lane>>4)*4 + reg.
    float* outF = (float*)Out + split * psz;
    ushort* outH = (ushort*)Out;
    const float* be = bias + (size_t)e * N;
    float bv[4];
#pragma unroll
    for (int nti = 0; nti < 4; nti++)
        bv[nti] = (split == 0) ? be[n0 + wn + nti * 16 + l16] : 0.f;
#pragma unroll
    for (int mti = 0; mti < 4; mti++) {
#pragma unroll
        for (int r = 0; r < 4; r++) {
            int lrow = wm + mti * 16 + quad * 4 + r;
            if (m0 + lrow < cnt) {
                int v = rowv[lrow];
                size_t base = (size_t)v * N;
#pragma unroll
                for (int nti = 0; nti < 4; nti++) {
                    int col = n0 + wn + nti * 16 + l16;
                    float val = acc[mti][nti][r] + bv[nti];
                    if (GELU) val = gelu_fast(val);
                    if (OUTBF16) outH[base + col] = f2bf(val);
                    else         outF[base + col] = val;
                }
            }
        }
    }
}

// ---------------------------------------------------------------------------
// out[t] = w0 * (ya[2t]+yb[2t]) + w1 * (ya[2t+1]+yb[2t+1])
// (split-K partial sum folded in; fully coalesced)
__global__ __launch_bounds__(256)
void combine_kernel(const float* __restrict__ y, const float* __restrict__ wslot,
                    float* __restrict__ out) {
    const float* y2 = y + (size_t)NTOK * TOPK * CDIM;   // split-1 partials
    int idx = blockIdx.x * 256 + threadIdx.x;     // one float4 each
    int c4 = idx & (CDIM / 4 - 1);
    int t = idx >> 8;                              // CDIM/4 == 256
    float w0 = wslot[2 * t], w1 = wslot[2 * t + 1];
    const float4* y0a = (const float4*)(y  + (size_t)(2 * t) * CDIM);
    const float4* y1a = (const float4*)(y  + (size_t)(2 * t + 1) * CDIM);
    const float4* y0b = (const float4*)(y2 + (size_t)(2 * t) * CDIM);
    const float4* y1b = (const float4*)(y2 + (size_t)(2 * t + 1) * CDIM);
    float4 a0 = y0a[c4], a1 = y0b[c4], b0 = y1a[c4], b1 = y1b[c4], o;
    o.x = w0 * (a0.x + a1.x) + w1 * (b0.x + b1.x);
    o.y = w0 * (a0.y + a1.y) + w1 * (b0.y + b1.y);
    o.z = w0 * (a0.z + a1.z) + w1 * (b0.z + b1.z);
    o.w = w0 * (a0.w + a1.w) + w1 * (b0.w + b1.w);
    ((float4*)(out + (size_t)t * CDIM))[c4] = o;
}

// ---------------------------------------------------------------------------
extern "C" void kernel_launch(void* const* d_in, const int* in_sizes, int n_in,
                              void* d_out, int out_size, void* d_ws, size_t ws_size,
                              hipStream_t stream) {
    const float* x  = (const float*)d_in[0];
    const float* Wg = (const float*)d_in[1];
    const float* bg = (const float*)d_in[2];
    const float* W1 = (const float*)d_in[3];
    const float* b1 = (const float*)d_in[4];
    const float* W2 = (const float*)d_in[5];
    const float* b2 = (const float*)d_in[6];
    float* out = (float*)d_out;
    char* ws = (char*)d_ws;

    // workspace layout (bytes)
    size_t off = 0;
    int*    counts = (int*)(ws + off);    off += 256;
    int*    tlist  = (int*)(ws + off);    off += (size_t)NEXP * NTOK * 4;        // 128 KB
    float*  wslot  = (float*)(ws + off);  off += (size_t)NTOK * TOPK * 4;        // 32 KB
    ushort* xbf    = (ushort*)(ws + off); off += (size_t)NTOK * CDIM * 2;        // 8 MB
    ushort* h      = (ushort*)(ws + off); off += (size_t)NTOK * TOPK * HDIM * 2; // 64 MB
    float*  y      = (float*)(ws + off);  off += (size_t)NTOK * TOPK * CDIM * 4 * 2; // 64 MB (2 split-K partials)

    hipMemsetAsync(counts, 0, NEXP * sizeof(int), stream);

    gate_kernel<<<NTOK / 4, 256, 0, stream>>>(x, Wg, bg, counts, tlist, wslot, xbf);

    // h[slot] = gelu(x @ W1 + b1), bf16.  W1 consumed native [C][H] f32.
    // flat grid = 8 experts x 32 mt x 32 nj
    moe_gemm<1, 1><<<NEXP * 32 * (HDIM / 128), 256, 0, stream>>>(
        xbf, W1, b1, tlist, counts, (void*)h, CDIM, HDIM, 1,
        HDIM / 128 - 1, 5, CDIM, 0);

    // y[split][slot] = h @ W2 (+ b2 on split 0), f32; split-K x2.
    // W2 consumed native [H][C] f32. flat grid = 8 x 32 x (8 n-tiles * 2)
    moe_gemm<0, 0><<<NEXP * 32 * (CDIM / 128) * 2, 256, 0, stream>>>(
        h, W2, b2, tlist, counts, (void*)y, HDIM, CDIM, 0,
        CDIM / 128 - 1, 3, HDIM / 2, (size_t)NTOK * TOPK * CDIM);

    combine_kernel<<<(NTOK * CDIM / 4) / 256, 256, 0, stream>>>(y, wslot, out);
}